// Round 4
// baseline (201.505 us; speedup 1.0000x reference)
//
#include <hip/hip_runtime.h>
#include <hip/hip_bf16.h>

#define N 384
#define D 128
#define TAU 0.25f
#define MARGIN 0.5f
#define NBLK 384

struct GramSh { float At[D][34]; float Bt[D][34]; float ps[4]; };
struct MainSh { float pn[6]; float pd[6]; };
union ShU { GramSh g; MainSh m; };

// Monotonic-counter grid barrier (no reset; targets strictly increase).
// Device-scope fences handle cross-XCD L2 non-coherence (release: writeback,
// acquire: invalidate). All 384 blocks are resident (34.9 KB LDS -> 4
// blocks/CU -> capacity 1024), so spinning cannot deadlock.
__device__ __forceinline__ void grid_bar(unsigned* bar, unsigned target) {
    __syncthreads();
    if (threadIdx.x == 0) {
        __threadfence();                       // release
        atomicAdd(bar, 1u);
        while (__hip_atomic_load(bar, __ATOMIC_RELAXED,
                                 __HIP_MEMORY_SCOPE_AGENT) < target) {
            __builtin_amdgcn_s_sleep(2);
        }
        __threadfence();                       // acquire
    }
    __syncthreads();
}

__global__ __launch_bounds__(NBLK) void k_fused(const float* __restrict__ xsrc,
                                                const float* __restrict__ xemb,
                                                float* __restrict__ xn_src,
                                                float* __restrict__ xn_emb,
                                                float* __restrict__ dsrc,
                                                float* __restrict__ demb,
                                                float* __restrict__ wsrc,
                                                float* __restrict__ tsum,
                                                float* __restrict__ accum,
                                                float* __restrict__ out) {
    __shared__ ShU sh;
    int bid = blockIdx.x;
    int t = threadIdx.x;
    unsigned* bar = (unsigned*)(accum + 3);

    // ---------- P1: L2-normalize row `bid` of both matrices --------------
    {
        int wv = t >> 6, lane = t & 63;
        if (wv < 2) {
            const float* x = wv ? xemb : xsrc;
            float* y       = wv ? xn_emb : xn_src;
            float2 v = ((const float2*)(x + (size_t)bid * D))[lane];
            float ss = v.x * v.x + v.y * v.y;
            #pragma unroll
            for (int o = 32; o > 0; o >>= 1) ss += __shfl_xor(ss, o);
            float inv = 1.0f / fmaxf(sqrtf(ss), 1e-12f);
            float2 o2 = {v.x * inv, v.y * inv};
            ((float2*)(y + (size_t)bid * D))[lane] = o2;
        }
    }
    grid_bar(bar, NBLK);

    // ---------- P2: 32x32 gram tiles -> distances (blocks 0-287) ---------
    if (bid < 288) {
        int mat = (bid >= 144) ? 1 : 0;
        int t2  = mat ? bid - 144 : bid;
        int bi = t2 / 12, bj = t2 % 12;
        const float* xn = mat ? xn_emb : xn_src;
        float* outm     = mat ? demb : dsrc;
        if (t < 256) {
            #pragma unroll
            for (int l = 0; l < 4; ++l) {
                int idx = t + l * 256;
                int row = idx >> 5;       // 0..31
                int c4  = idx & 31;       // float4 index within row
                float4 va = ((const float4*)(xn + (size_t)(bi * 32 + row) * D))[c4];
                sh.g.At[c4 * 4 + 0][row] = va.x; sh.g.At[c4 * 4 + 1][row] = va.y;
                sh.g.At[c4 * 4 + 2][row] = va.z; sh.g.At[c4 * 4 + 3][row] = va.w;
                float4 vb = ((const float4*)(xn + (size_t)(bj * 32 + row) * D))[c4];
                sh.g.Bt[c4 * 4 + 0][row] = vb.x; sh.g.Bt[c4 * 4 + 1][row] = vb.y;
                sh.g.Bt[c4 * 4 + 2][row] = vb.z; sh.g.Bt[c4 * 4 + 3][row] = vb.w;
            }
        }
        __syncthreads();
        float s_tile = 0.f;
        if (t < 256) {
            int tx = t & 15, ty = t >> 4;
            float a00 = 0.f, a01 = 0.f, a10 = 0.f, a11 = 0.f;
            #pragma unroll 8
            for (int k = 0; k < D; k++) {
                float x0 = sh.g.At[k][2 * ty], x1 = sh.g.At[k][2 * ty + 1];
                float y0 = sh.g.Bt[k][2 * tx], y1 = sh.g.Bt[k][2 * tx + 1];
                a00 = fmaf(x0, y0, a00); a01 = fmaf(x0, y1, a01);
                a10 = fmaf(x1, y0, a10); a11 = fmaf(x1, y1, a11);
            }
            float d00 = 1.f - a00, d01 = 1.f - a01, d10 = 1.f - a10, d11 = 1.f - a11;
            int r0 = bi * 32 + 2 * ty, c0 = bj * 32 + 2 * tx;
            outm[(size_t)r0 * N + c0]           = d00;
            outm[(size_t)r0 * N + c0 + 1]       = d01;
            outm[(size_t)(r0 + 1) * N + c0]     = d10;
            outm[(size_t)(r0 + 1) * N + c0 + 1] = d11;
            if (!mat) s_tile = d00 + d01 + d10 + d11;
        }
        if (!mat) {
            #pragma unroll
            for (int o = 32; o > 0; o >>= 1) s_tile += __shfl_xor(s_tile, o);
            if (t < 256 && (t & 63) == 0) sh.g.ps[t >> 6] = s_tile;
            __syncthreads();
            if (t == 0) tsum[t2] = sh.g.ps[0] + sh.g.ps[1] + sh.g.ps[2] + sh.g.ps[3];
        }
    }
    grid_bar(bar, 2 * NBLK);

    // ---------- P2.5: wp = exp(-(d/mean)/tau), one element per thread ----
    {
        float total = 0.f;
        #pragma unroll
        for (int j = 0; j < 144; ++j) total += tsum[j];
        float mean  = total * (1.0f / (float)(N * N));
        float scale = 1.0f / (fmaxf(mean, 1e-12f) * TAU);
        int idx = bid * N + t;                 // covers exactly N*N
        wsrc[idx] = expf(-dsrc[idx] * scale);
    }
    grid_bar(bar, 3 * NBLK);

    // ---------- P3: per-(i,j) semihard max over k + fused reduction ------
    {
        const float* der = demb + (size_t)bid * N;
        const float* wpr = wsrc + (size_t)bid * N;
        float c = MARGIN + der[t];             // tl = c - de[k]
        float m0 = 0.f, m1 = 0.f, m2 = 0.f, m3 = 0.f;
        #pragma unroll 2
        for (int k = 0; k < N; k += 4) {
            float d0 = der[k], d1 = der[k + 1], d2 = der[k + 2], d3 = der[k + 3];
            float w0 = wpr[k], w1 = wpr[k + 1], w2 = wpr[k + 2], w3 = wpr[k + 3];
            float tl0 = c - d0; float v0 = tl0 * (1.f - w0);
            v0 = (tl0 <= MARGIN) ? v0 : 0.f; m0 = fmaxf(m0, v0);
            float tl1 = c - d1; float v1 = tl1 * (1.f - w1);
            v1 = (tl1 <= MARGIN) ? v1 : 0.f; m1 = fmaxf(m1, v1);
            float tl2 = c - d2; float v2 = tl2 * (1.f - w2);
            v2 = (tl2 <= MARGIN) ? v2 : 0.f; m2 = fmaxf(m2, v2);
            float tl3 = c - d3; float v3 = tl3 * (1.f - w3);
            v3 = (tl3 <= MARGIN) ? v3 : 0.f; m3 = fmaxf(m3, v3);
        }
        float m = fmaxf(fmaxf(m0, m1), fmaxf(m2, m3));
        float w = wpr[t];
        float numc = w * w * m;
        float denc = w;
        #pragma unroll
        for (int o = 32; o > 0; o >>= 1) {
            numc += __shfl_xor(numc, o);
            denc += __shfl_xor(denc, o);
        }
        if ((t & 63) == 0) { sh.m.pn[t >> 6] = numc; sh.m.pd[t >> 6] = denc; }
        __syncthreads();
        if (t == 0) {
            float sn = 0.f, sd = 0.f;
            #pragma unroll
            for (int wv = 0; wv < 6; wv++) { sn += sh.m.pn[wv]; sd += sh.m.pd[wv]; }
            atomicAdd(&accum[0], sn);
            atomicAdd(&accum[1], sd);
            __threadfence();
            unsigned tk = atomicAdd((unsigned*)(accum + 2), 1u);
            if (tk == (unsigned)(NBLK - 1)) {          // last block finalizes
                float num = atomicAdd(&accum[0], 0.f); // coherent reads
                float den = atomicAdd(&accum[1], 0.f);
                out[0] = (den > 0.f) ? num / den : 0.f;
            }
        }
    }
}

extern "C" void kernel_launch(void* const* d_in, const int* in_sizes, int n_in,
                              void* d_out, int out_size, void* d_ws, size_t ws_size,
                              hipStream_t stream) {
    const float* src = (const float*)d_in[0];
    const float* emb = (const float*)d_in[1];
    float* out = (float*)d_out;

    float* ws = (float*)d_ws;
    float* xn_src = ws;                      // N*D
    float* xn_emb = xn_src + N * D;          // N*D
    float* dsrc   = xn_emb + N * D;          // N*N
    float* demb   = dsrc + N * N;            // N*N
    float* wsrc   = demb + N * N;            // N*N
    float* tsum   = wsrc + N * N;            // 144
    float* accum  = tsum + 144;              // [0]=num [1]=den [2]=ticket [3]=bar

    hipMemsetAsync(accum, 0, 4 * sizeof(float), stream);
    k_fused<<<NBLK, NBLK, 0, stream>>>(src, emb, xn_src, xn_emb, dsrc, demb,
                                       wsrc, tsum, accum, out);
}

// Round 6
// 97.085 us; speedup vs baseline: 2.0755x; 2.0755x over previous
//
#include <hip/hip_runtime.h>
#include <hip/hip_bf16.h>

#define N 384
#define D 128
#define TAU 0.25f
#define MARGIN 0.5f

// ---------------- K1: L2-normalize rows; block 0 zeroes accum -----------
// grid: 2*N blocks of 64 threads; block b<N -> src row b, else emb row b-N
__global__ __launch_bounds__(64) void k_norm(const float* __restrict__ src,
                                             const float* __restrict__ emb,
                                             float* __restrict__ xn_src,
                                             float* __restrict__ xn_emb,
                                             float* __restrict__ accum) {
    int b = blockIdx.x;
    int lane = threadIdx.x;               // 0..63, D/2=64 float2 per row
    if (b == 0 && lane == 0) {
        accum[0] = 0.f; accum[1] = 0.f;
        ((unsigned int*)accum)[2] = 0u;   // ticket
    }
    const float* x;
    float* y;
    int row;
    if (b < N) { x = src; y = xn_src; row = b; }
    else       { x = emb; y = xn_emb; row = b - N; }
    float2 v = ((const float2*)(x + (size_t)row * D))[lane];
    float ss = v.x * v.x + v.y * v.y;
    #pragma unroll
    for (int o = 32; o > 0; o >>= 1) ss += __shfl_xor(ss, o);
    float inv = 1.0f / fmaxf(sqrtf(ss), 1e-12f);
    float2 o2 = {v.x * inv, v.y * inv};
    ((float2*)(y + (size_t)row * D))[lane] = o2;
}

// ---------------- K2: scale from closed-form mean -----------------------
// sum_ij sim_ij = || sum_i xn_i ||^2  ->  mean(dist) = (N^2 - that)/N^2.
// One block, 256 threads: thread (c = t&127, h = t>>7) sums 192 rows of col c.
__global__ __launch_bounds__(256) void k_scale(const float* __restrict__ xn_src,
                                               float* __restrict__ accum) {
    __shared__ float sv[128];
    __shared__ float ps[2];
    int t = threadIdx.x;
    int c = t & 127, h = t >> 7;
    float s = 0.f;
    const float* p = xn_src + (size_t)h * 192 * D + c;
    #pragma unroll 8
    for (int r = 0; r < 192; ++r) s += p[(size_t)r * D];
    if (h == 0) sv[c] = s;
    __syncthreads();
    if (h == 1) sv[c] += s;
    __syncthreads();
    if (t < 128) {
        float v = sv[t];
        float sq = v * v;
        #pragma unroll
        for (int o = 32; o > 0; o >>= 1) sq += __shfl_xor(sq, o);
        if ((t & 63) == 0) ps[t >> 6] = sq;
    }
    __syncthreads();
    if (t == 0) {
        float sum_sim = ps[0] + ps[1];
        float nn = (float)N * (float)N;
        float mean = (nn - sum_sim) * (1.0f / nn);
        accum[3] = 1.0f / (fmaxf(mean, 1e-12f) * TAU);
    }
}

// ---------------- K3: Gram tiles; src -> wp directly, emb -> demb -------
// grid: 288 blocks of 256 threads, one 32x32 tile each (2x2 micro-tile).
__global__ __launch_bounds__(256) void k_gram(const float* __restrict__ xn_src,
                                              const float* __restrict__ xn_emb,
                                              float* __restrict__ wsrc,
                                              float* __restrict__ demb,
                                              const float* __restrict__ accum) {
    __shared__ float At[D][34];
    __shared__ float Bt[D][34];
    int bid = blockIdx.x;
    int mat = (bid >= 144) ? 1 : 0;
    int t2  = mat ? bid - 144 : bid;
    int bi = t2 / 12, bj = t2 % 12;
    const float* xn = mat ? xn_emb : xn_src;
    float* outm     = mat ? demb : wsrc;
    float scale = accum[3];              // uniform -> s_load
    int lin = threadIdx.x;
    #pragma unroll
    for (int l = 0; l < 4; ++l) {
        int idx = lin + l * 256;
        int row = idx >> 5;        // 0..31
        int c4  = idx & 31;        // float4 index within row
        float4 va = ((const float4*)(xn + (size_t)(bi * 32 + row) * D))[c4];
        At[c4 * 4 + 0][row] = va.x; At[c4 * 4 + 1][row] = va.y;
        At[c4 * 4 + 2][row] = va.z; At[c4 * 4 + 3][row] = va.w;
        float4 vb = ((const float4*)(xn + (size_t)(bj * 32 + row) * D))[c4];
        Bt[c4 * 4 + 0][row] = vb.x; Bt[c4 * 4 + 1][row] = vb.y;
        Bt[c4 * 4 + 2][row] = vb.z; Bt[c4 * 4 + 3][row] = vb.w;
    }
    __syncthreads();
    int tx = lin & 15, ty = lin >> 4;
    float a00 = 0.f, a01 = 0.f, a10 = 0.f, a11 = 0.f;
    #pragma unroll 8
    for (int k = 0; k < D; k++) {
        float x0 = At[k][2 * ty], x1 = At[k][2 * ty + 1];
        float y0 = Bt[k][2 * tx], y1 = Bt[k][2 * tx + 1];
        a00 = fmaf(x0, y0, a00); a01 = fmaf(x0, y1, a01);
        a10 = fmaf(x1, y0, a10); a11 = fmaf(x1, y1, a11);
    }
    float d00 = 1.f - a00, d01 = 1.f - a01, d10 = 1.f - a10, d11 = 1.f - a11;
    if (!mat) {            // src: emit teacher pos-weights directly
        d00 = expf(-d00 * scale); d01 = expf(-d01 * scale);
        d10 = expf(-d10 * scale); d11 = expf(-d11 * scale);
    }
    int r0 = bi * 32 + 2 * ty, c0 = bj * 32 + 2 * tx;
    outm[(size_t)r0 * N + c0]           = d00;
    outm[(size_t)r0 * N + c0 + 1]       = d01;
    outm[(size_t)(r0 + 1) * N + c0]     = d10;
    outm[(size_t)(r0 + 1) * N + c0 + 1] = d11;
}

// ---------------- K4: semihard max over k + reduction + finalize --------
// grid: N blocks of N threads; k-streams via uniform scalar loads.
__global__ __launch_bounds__(N) void k_main(const float* __restrict__ wsrc,
                                            const float* __restrict__ demb,
                                            float* __restrict__ accum,
                                            float* __restrict__ out) {
    __shared__ float pn[6], pd[6];
    int i = blockIdx.x;
    int t = threadIdx.x;
    const float* der = demb + (size_t)i * N;
    const float* wpr = wsrc + (size_t)i * N;
    float c = MARGIN + der[t];             // tl = c - de[k]
    float m0 = 0.f, m1 = 0.f, m2 = 0.f, m3 = 0.f;
    #pragma unroll 2
    for (int k = 0; k < N; k += 4) {
        float d0 = der[k], d1 = der[k + 1], d2 = der[k + 2], d3 = der[k + 3];
        float w0 = wpr[k], w1 = wpr[k + 1], w2 = wpr[k + 2], w3 = wpr[k + 3];
        float tl0 = c - d0; float v0 = fmaf(-tl0, w0, tl0);   // tl*(1-w)
        v0 = (tl0 <= MARGIN) ? v0 : 0.f; m0 = fmaxf(m0, v0);
        float tl1 = c - d1; float v1 = fmaf(-tl1, w1, tl1);
        v1 = (tl1 <= MARGIN) ? v1 : 0.f; m1 = fmaxf(m1, v1);
        float tl2 = c - d2; float v2 = fmaf(-tl2, w2, tl2);
        v2 = (tl2 <= MARGIN) ? v2 : 0.f; m2 = fmaxf(m2, v2);
        float tl3 = c - d3; float v3 = fmaf(-tl3, w3, tl3);
        v3 = (tl3 <= MARGIN) ? v3 : 0.f; m3 = fmaxf(m3, v3);
    }
    float m = fmaxf(fmaxf(m0, m1), fmaxf(m2, m3));
    float w = wpr[t];
    float numc = w * w * m;
    float denc = w;
    #pragma unroll
    for (int o = 32; o > 0; o >>= 1) {
        numc += __shfl_xor(numc, o);
        denc += __shfl_xor(denc, o);
    }
    if ((t & 63) == 0) { pn[t >> 6] = numc; pd[t >> 6] = denc; }
    __syncthreads();
    if (t == 0) {
        float sn = 0.f, sd = 0.f;
        #pragma unroll
        for (int wv = 0; wv < 6; wv++) { sn += pn[wv]; sd += pd[wv]; }
        atomicAdd(&accum[0], sn);
        atomicAdd(&accum[1], sd);
        __threadfence();
        unsigned tk = atomicAdd((unsigned*)(accum + 2), 1u);
        if (tk == (unsigned)(N - 1)) {             // last block finalizes
            float num = atomicAdd(&accum[0], 0.f); // coherent reads
            float den = atomicAdd(&accum[1], 0.f);
            out[0] = (den > 0.f) ? num / den : 0.f;
        }
    }
}

extern "C" void kernel_launch(void* const* d_in, const int* in_sizes, int n_in,
                              void* d_out, int out_size, void* d_ws, size_t ws_size,
                              hipStream_t stream) {
    const float* src = (const float*)d_in[0];
    const float* emb = (const float*)d_in[1];
    float* out = (float*)d_out;

    float* ws = (float*)d_ws;
    float* xn_src = ws;                      // N*D
    float* xn_emb = xn_src + N * D;          // N*D
    float* wsrc   = xn_emb + N * D;          // N*N teacher pos-weights
    float* demb   = wsrc + N * N;            // N*N emb distances
    float* accum  = demb + N * N;            // [0]=num [1]=den [2]=ticket [3]=scale

    k_norm<<<2 * N, 64, 0, stream>>>(src, emb, xn_src, xn_emb, accum);
    k_scale<<<1, 256, 0, stream>>>(xn_src, accum);
    k_gram<<<288, 256, 0, stream>>>(xn_src, xn_emb, wsrc, demb, accum);
    k_main<<<N, N, 0, stream>>>(wsrc, demb, accum, out);
}

// Round 7
// 93.573 us; speedup vs baseline: 2.1535x; 1.0375x over previous
//
#include <hip/hip_runtime.h>
#include <hip/hip_bf16.h>

#define N 384
#define D 128
#define TAU 0.25f
#define MARGIN 0.5f

// ---------------- K1: L2-normalize rows; block 0 zeroes accum -----------
// grid: 2*N blocks of 64 threads; block b<N -> src row b, else emb row b-N
__global__ __launch_bounds__(64) void k_norm(const float* __restrict__ src,
                                             const float* __restrict__ emb,
                                             float* __restrict__ xn_src,
                                             float* __restrict__ xn_emb,
                                             float* __restrict__ accum) {
    int b = blockIdx.x;
    int lane = threadIdx.x;               // 0..63, D/2=64 float2 per row
    if (b == 0 && lane == 0) {
        accum[0] = 0.f; accum[1] = 0.f;
        ((unsigned int*)accum)[2] = 0u;   // ticket
    }
    const float* x;
    float* y;
    int row;
    if (b < N) { x = src; y = xn_src; row = b; }
    else       { x = emb; y = xn_emb; row = b - N; }
    float2 v = ((const float2*)(x + (size_t)row * D))[lane];
    float ss = v.x * v.x + v.y * v.y;
    #pragma unroll
    for (int o = 32; o > 0; o >>= 1) ss += __shfl_xor(ss, o);
    float inv = 1.0f / fmaxf(sqrtf(ss), 1e-12f);
    float2 o2 = {v.x * inv, v.y * inv};
    ((float2*)(y + (size_t)row * D))[lane] = o2;
}

// ---------------- K2: Gram tiles; src -> wp directly, emb -> demb -------
// grid: 288 blocks of 256 threads, one 32x32 tile each (2x2 micro-tile).
// Src blocks redundantly compute scale from the closed-form mean:
//   sum_ij sim_ij = ||sum_i xn_i||^2, mean = (N^2 - that)/N^2.
// The per-block column-sum (192KB, L2-resident) is issued BEFORE the GEMM
// loop so its loads hide under the FMA work; 144 blocks x 27MB total L2
// traffic ~ 0.8us aggregate. Fully parallel -- no serial 1-block stage.
__global__ __launch_bounds__(256) void k_gram(const float* __restrict__ xn_src,
                                              const float* __restrict__ xn_emb,
                                              float* __restrict__ wsrc,
                                              float* __restrict__ demb) {
    __shared__ float At[D][34];
    __shared__ float Bt[D][34];
    __shared__ float sv[128];
    __shared__ float ps[2];
    __shared__ float s_scale;
    int bid = blockIdx.x;
    int mat = (bid >= 144) ? 1 : 0;
    int t2  = mat ? bid - 144 : bid;
    int bi = t2 / 12, bj = t2 % 12;
    const float* xn = mat ? xn_emb : xn_src;
    float* outm     = mat ? demb : wsrc;
    int lin = threadIdx.x;

    // (a) src blocks: per-thread partial column sum (c = lin&127, h = lin>>7)
    float cs = 0.f;
    if (!mat) {
        int c = lin & 127, h = lin >> 7;
        const float* p = xn_src + (size_t)h * 192 * D + c;
        #pragma unroll 8
        for (int r = 0; r < 192; ++r) cs += p[(size_t)r * D];
    }

    // (b) stage 32x32 tiles, transposed
    #pragma unroll
    for (int l = 0; l < 4; ++l) {
        int idx = lin + l * 256;
        int row = idx >> 5;        // 0..31
        int c4  = idx & 31;        // float4 index within row
        float4 va = ((const float4*)(xn + (size_t)(bi * 32 + row) * D))[c4];
        At[c4 * 4 + 0][row] = va.x; At[c4 * 4 + 1][row] = va.y;
        At[c4 * 4 + 2][row] = va.z; At[c4 * 4 + 3][row] = va.w;
        float4 vb = ((const float4*)(xn + (size_t)(bj * 32 + row) * D))[c4];
        Bt[c4 * 4 + 0][row] = vb.x; Bt[c4 * 4 + 1][row] = vb.y;
        Bt[c4 * 4 + 2][row] = vb.z; Bt[c4 * 4 + 3][row] = vb.w;
    }
    __syncthreads();

    // (c) 2x2 micro GEMM over K=128
    int tx = lin & 15, ty = lin >> 4;
    float a00 = 0.f, a01 = 0.f, a10 = 0.f, a11 = 0.f;
    #pragma unroll 8
    for (int k = 0; k < D; k++) {
        float x0 = At[k][2 * ty], x1 = At[k][2 * ty + 1];
        float y0 = Bt[k][2 * tx], y1 = Bt[k][2 * tx + 1];
        a00 = fmaf(x0, y0, a00); a01 = fmaf(x0, y1, a01);
        a10 = fmaf(x1, y0, a10); a11 = fmaf(x1, y1, a11);
    }
    float d00 = 1.f - a00, d01 = 1.f - a01, d10 = 1.f - a10, d11 = 1.f - a11;

    if (!mat) {
        // (d) finish scale reduction (identical summation order to the
        // proven k_scale kernel: halves add, square, 64-shfl, pair sum)
        int c = lin & 127, h = lin >> 7;
        if (h == 0) sv[c] = cs;
        __syncthreads();
        if (h == 1) sv[c] += cs;
        __syncthreads();
        if (lin < 128) {
            float v = sv[lin];
            float sq = v * v;
            #pragma unroll
            for (int o = 32; o > 0; o >>= 1) sq += __shfl_xor(sq, o);
            if ((lin & 63) == 0) ps[lin >> 6] = sq;
        }
        __syncthreads();
        if (lin == 0) {
            float sum_sim = ps[0] + ps[1];
            float nn = (float)N * (float)N;
            float mean = (nn - sum_sim) * (1.0f / nn);
            s_scale = 1.0f / (fmaxf(mean, 1e-12f) * TAU);
        }
        __syncthreads();
        float scale = s_scale;
        d00 = expf(-d00 * scale); d01 = expf(-d01 * scale);
        d10 = expf(-d10 * scale); d11 = expf(-d11 * scale);
    }
    int r0 = bi * 32 + 2 * ty, c0 = bj * 32 + 2 * tx;
    outm[(size_t)r0 * N + c0]           = d00;
    outm[(size_t)r0 * N + c0 + 1]       = d01;
    outm[(size_t)(r0 + 1) * N + c0]     = d10;
    outm[(size_t)(r0 + 1) * N + c0 + 1] = d11;
}

// ---------------- K3: semihard max over k + reduction + finalize --------
// grid: N blocks of N threads; k-streams via uniform scalar loads.
__global__ __launch_bounds__(N) void k_main(const float* __restrict__ wsrc,
                                            const float* __restrict__ demb,
                                            float* __restrict__ accum,
                                            float* __restrict__ out) {
    __shared__ float pn[6], pd[6];
    int i = blockIdx.x;
    int t = threadIdx.x;
    const float* der = demb + (size_t)i * N;
    const float* wpr = wsrc + (size_t)i * N;
    float c = MARGIN + der[t];             // tl = c - de[k]
    float m0 = 0.f, m1 = 0.f, m2 = 0.f, m3 = 0.f;
    #pragma unroll 2
    for (int k = 0; k < N; k += 4) {
        float d0 = der[k], d1 = der[k + 1], d2 = der[k + 2], d3 = der[k + 3];
        float w0 = wpr[k], w1 = wpr[k + 1], w2 = wpr[k + 2], w3 = wpr[k + 3];
        float tl0 = c - d0; float v0 = fmaf(-tl0, w0, tl0);   // tl*(1-w)
        v0 = (tl0 <= MARGIN) ? v0 : 0.f; m0 = fmaxf(m0, v0);
        float tl1 = c - d1; float v1 = fmaf(-tl1, w1, tl1);
        v1 = (tl1 <= MARGIN) ? v1 : 0.f; m1 = fmaxf(m1, v1);
        float tl2 = c - d2; float v2 = fmaf(-tl2, w2, tl2);
        v2 = (tl2 <= MARGIN) ? v2 : 0.f; m2 = fmaxf(m2, v2);
        float tl3 = c - d3; float v3 = fmaf(-tl3, w3, tl3);
        v3 = (tl3 <= MARGIN) ? v3 : 0.f; m3 = fmaxf(m3, v3);
    }
    float m = fmaxf(fmaxf(m0, m1), fmaxf(m2, m3));
    float w = wpr[t];
    float numc = w * w * m;
    float denc = w;
    #pragma unroll
    for (int o = 32; o > 0; o >>= 1) {
        numc += __shfl_xor(numc, o);
        denc += __shfl_xor(denc, o);
    }
    if ((t & 63) == 0) { pn[t >> 6] = numc; pd[t >> 6] = denc; }
    __syncthreads();
    if (t == 0) {
        float sn = 0.f, sd = 0.f;
        #pragma unroll
        for (int wv = 0; wv < 6; wv++) { sn += pn[wv]; sd += pd[wv]; }
        atomicAdd(&accum[0], sn);
        atomicAdd(&accum[1], sd);
        __threadfence();
        unsigned tk = atomicAdd((unsigned*)(accum + 2), 1u);
        if (tk == (unsigned)(N - 1)) {             // last block finalizes
            float num = atomicAdd(&accum[0], 0.f); // coherent reads
            float den = atomicAdd(&accum[1], 0.f);
            out[0] = (den > 0.f) ? num / den : 0.f;
        }
    }
}

extern "C" void kernel_launch(void* const* d_in, const int* in_sizes, int n_in,
                              void* d_out, int out_size, void* d_ws, size_t ws_size,
                              hipStream_t stream) {
    const float* src = (const float*)d_in[0];
    const float* emb = (const float*)d_in[1];
    float* out = (float*)d_out;

    float* ws = (float*)d_ws;
    float* xn_src = ws;                      // N*D
    float* xn_emb = xn_src + N * D;          // N*D
    float* wsrc   = xn_emb + N * D;          // N*N teacher pos-weights
    float* demb   = wsrc + N * N;            // N*N emb distances
    float* accum  = demb + N * N;            // [0]=num [1]=den [2]=ticket

    k_norm<<<2 * N, 64, 0, stream>>>(src, emb, xn_src, xn_emb, accum);
    k_gram<<<288, 256, 0, stream>>>(xn_src, xn_emb, wsrc, demb);
    k_main<<<N, N, 0, stream>>>(wsrc, demb, accum, out);
}